// Round 1
// baseline (2250.862 us; speedup 1.0000x reference)
//
#include <hip/hip_runtime.h>

#define BLK 128
#define NLEV 16

__global__ __launch_bounds__(BLK)
void henc_kernel(const float* __restrict__ xs, const float* __restrict__ table,
                 float* __restrict__ out, int n)
{
    __shared__ float sbuf[BLK * 71];
    // cumulative level offsets (rows of float2) -- from reference OFFSETS
    constexpr int kOff[NLEV] = {0, 4913, 40850, 315475, 839763, 1364051, 1888339,
                                2412627, 2936915, 3461203, 3985491, 4509779,
                                5034067, 5558355, 6082643, 6606931};
    const int tid  = threadIdx.x;
    const int base = blockIdx.x * BLK;
    const int pi   = base + tid;

    float px = 0.f, py = 0.f, pz = 0.f;
    if (pi < n) {
        px = xs[3 * pi + 0];
        py = xs[3 * pi + 1];
        pz = xs[3 * pi + 2];
    }

    float* srow = sbuf + tid * 71;
    const float2* __restrict__ tab = (const float2*)table;

    #pragma unroll
    for (int l = 0; l < NLEV; ++l) {
        const int res = 16 << l;                    // floor(16 * 2^l)
        const float2* __restrict__ tl = tab + kOff[l];
        const float fres = (float)res;

        float posx = px * fres, posy = py * fres, posz = pz * fres;
        float fxf = floorf(posx), fyf = floorf(posy), fzf = floorf(posz);
        float rx = posx - fxf, ry = posy - fyf, rz = posz - fzf;
        int ix = (int)fxf, iy = (int)fyf, iz = (int)fzf;

        int x0 = min(max(ix, 0), res), x1 = min(ix + 1, res);
        int y0 = min(max(iy, 0), res), y1 = min(iy + 1, res);
        int z0 = min(max(iz, 0), res), z1 = min(iz + 1, res);

        unsigned i000, i001, i010, i011, i100, i101, i110, i111;
        if (l < 3) {
            // dense stride indexing: idx = cx + cy*(res+1) + cz*(res+1)^2
            const unsigned r1 = (unsigned)(res + 1);
            const unsigned r2 = r1 * r1;
            unsigned ax0 = (unsigned)x0, ax1 = (unsigned)x1;
            unsigned by0 = (unsigned)y0 * r1, by1 = (unsigned)y1 * r1;
            unsigned cz0 = (unsigned)z0 * r2, cz1 = (unsigned)z1 * r2;
            i000 = ax0 + by0 + cz0; i001 = ax0 + by0 + cz1;
            i010 = ax0 + by1 + cz0; i011 = ax0 + by1 + cz1;
            i100 = ax1 + by0 + cz0; i101 = ax1 + by0 + cz1;
            i110 = ax1 + by1 + cz0; i111 = ax1 + by1 + cz1;
        } else {
            // spatial hash: (c0*1 ^ c1*2654435761 ^ c2*805459861) % 2^19
            unsigned ax0 = (unsigned)x0, ax1 = (unsigned)x1;
            unsigned by0 = (unsigned)y0 * 2654435761u, by1 = (unsigned)y1 * 2654435761u;
            unsigned cz0 = (unsigned)z0 * 805459861u,  cz1 = (unsigned)z1 * 805459861u;
            i000 = (ax0 ^ by0 ^ cz0) & 524287u; i001 = (ax0 ^ by0 ^ cz1) & 524287u;
            i010 = (ax0 ^ by1 ^ cz0) & 524287u; i011 = (ax0 ^ by1 ^ cz1) & 524287u;
            i100 = (ax1 ^ by0 ^ cz0) & 524287u; i101 = (ax1 ^ by0 ^ cz1) & 524287u;
            i110 = (ax1 ^ by1 ^ cz0) & 524287u; i111 = (ax1 ^ by1 ^ cz1) & 524287u;
        }

        float2 v000 = tl[i000], v001 = tl[i001], v010 = tl[i010], v011 = tl[i011];
        float2 v100 = tl[i100], v101 = tl[i101], v110 = tl[i110], v111 = tl[i111];

        float wx1 = rx, wx0 = 1.f - rx;
        float wy1 = ry, wy0 = 1.f - ry;
        float wz1 = rz, wz0 = 1.f - rz;

        float f0, f1, w;
        w = wx0 * wy0 * wz0; f0  = w * v000.x; f1  = w * v000.y;
        w = wx0 * wy0 * wz1; f0 += w * v001.x; f1 += w * v001.y;
        w = wx0 * wy1 * wz0; f0 += w * v010.x; f1 += w * v010.y;
        w = wx0 * wy1 * wz1; f0 += w * v011.x; f1 += w * v011.y;
        w = wx1 * wy0 * wz0; f0 += w * v100.x; f1 += w * v100.y;
        w = wx1 * wy0 * wz1; f0 += w * v101.x; f1 += w * v101.y;
        w = wx1 * wy1 * wz0; f0 += w * v110.x; f1 += w * v110.y;
        w = wx1 * wy1 * wz1; f0 += w * v111.x; f1 += w * v111.y;

        srow[2 * l]     = f0;
        srow[2 * l + 1] = f1;
    }

    // positional encoding: [x, {per-freq: sin(x*2^f)*3 then cos(x*2^f)*3}]
    srow[32] = px; srow[33] = py; srow[34] = pz;
    float coef = 1.f;
    #pragma unroll
    for (int f = 0; f < 6; ++f) {
        float s, c;
        __sincosf(px * coef, &s, &c); srow[35 + 6*f + 0] = s; srow[35 + 6*f + 3] = c;
        __sincosf(py * coef, &s, &c); srow[35 + 6*f + 1] = s; srow[35 + 6*f + 4] = c;
        __sincosf(pz * coef, &s, &c); srow[35 + 6*f + 2] = s; srow[35 + 6*f + 5] = c;
        coef *= 2.f;
    }

    __syncthreads();

    // coalesced write-out of the block's [BLK,71] tile
    const int nvalid = min(BLK, n - base);
    float* obase = out + (size_t)base * 71;
    if (nvalid == BLK) {
        const float4* s4 = (const float4*)sbuf;
        float4* o4 = (float4*)obase;
        #pragma unroll 1
        for (int i = tid; i < (BLK * 71) / 4; i += BLK) o4[i] = s4[i];
    } else {
        #pragma unroll 1
        for (int i = tid; i < nvalid * 71; i += BLK) obase[i] = sbuf[i];
    }
}

extern "C" void kernel_launch(void* const* d_in, const int* in_sizes, int n_in,
                              void* d_out, int out_size, void* d_ws, size_t ws_size,
                              hipStream_t stream) {
    const float* xs    = (const float*)d_in[0];
    const float* table = (const float*)d_in[1];
    float* out = (float*)d_out;
    const int n = in_sizes[0] / 3;          // 2,000,000 points
    const int grid = (n + BLK - 1) / BLK;
    hipLaunchKernelGGL(henc_kernel, dim3(grid), dim3(BLK), 0, stream,
                       xs, table, out, n);
}